// Round 1
// baseline (3367.297 us; speedup 1.0000x reference)
//
#include <hip/hip_runtime.h>

#define N_USERS 100000
#define N_ITEMS 50000
#define N_NODES 150000
#define DIM 64
#define RDIM 32
#define NNZ_E 4800000
#define EMB_TOT (N_NODES * DIM)   // 9,600,000 floats

// ---------------------------------------------------------------------------
// init: ego = concat(user, item); acc(d_out) = same
// ---------------------------------------------------------------------------
__global__ __launch_bounds__(256) void k_init(const float4* __restrict__ ue,
                                              const float4* __restrict__ ie,
                                              float4* __restrict__ ego,
                                              float4* __restrict__ acc) {
    int i = blockIdx.x * 256 + threadIdx.x;           // over EMB_TOT/4 float4s
    if (i >= EMB_TOT / 4) return;
    const int USER4 = N_USERS * DIM / 4;
    float4 v = (i < USER4) ? ue[i] : ie[i - USER4];
    ego[i] = v;
    acc[i] = v;
}

// ---------------------------------------------------------------------------
// spmm: y[rows[e]] += vals[e] * x[cols[e]]   (one wave per edge, lane = dim)
// ---------------------------------------------------------------------------
__global__ __launch_bounds__(256) void k_spmm(const int* __restrict__ rows,
                                              const int* __restrict__ cols,
                                              const float* __restrict__ vals,
                                              const float* __restrict__ x,
                                              float* __restrict__ y) {
    long long t = (long long)blockIdx.x * 256 + threadIdx.x;
    int e = (int)(t >> 6);
    int d = (int)(t & 63);
    if (e >= NNZ_E) return;
    int r = rows[e];
    int c = cols[e];
    float v = vals[e];
    atomicAdd(&y[(long long)r * DIM + d], v * x[(long long)c * DIM + d]);
}

// ---------------------------------------------------------------------------
// acc += ego_new   (vectorized)
// ---------------------------------------------------------------------------
__global__ __launch_bounds__(256) void k_accadd(const float4* __restrict__ e,
                                                float4* __restrict__ acc) {
    int i = blockIdx.x * 256 + threadIdx.x;
    if (i >= EMB_TOT / 4) return;
    float4 a = acc[i];
    float4 b = e[i];
    a.x += b.x; a.y += b.y; a.z += b.z; a.w += b.w;
    acc[i] = a;
}

// ---------------------------------------------------------------------------
// zero the loss accumulator
// ---------------------------------------------------------------------------
__global__ void k_zero_loss(float* p) {
    if (blockIdx.x == 0 && threadIdx.x == 0) *p = 0.0f;
}

// ---------------------------------------------------------------------------
// final: per-row  e = acc/4 ; h = W1 e + b1 ; g = W2 h + b2 ;
//        out_row = g (in place over acc) ; loss += ||g - e||^2
// One thread per node row; weights in LDS (all-lane broadcast reads).
// ---------------------------------------------------------------------------
__global__ __launch_bounds__(256) void k_mlp_loss(float* __restrict__ out,
                                                  const float* __restrict__ w1,
                                                  const float* __restrict__ b1,
                                                  const float* __restrict__ w2,
                                                  const float* __restrict__ b2,
                                                  float* __restrict__ loss) {
    __shared__ float sw1[RDIM][DIM];   // fc1_w[j][d]
    __shared__ float sw2[DIM][RDIM];   // fc2_w[k][j]
    __shared__ float sb1[RDIM];
    __shared__ float sb2[DIM];

    for (int i = threadIdx.x; i < RDIM * DIM; i += 256) sw1[i / DIM][i % DIM] = w1[i];
    for (int i = threadIdx.x; i < DIM * RDIM; i += 256) sw2[i / RDIM][i % RDIM] = w2[i];
    if (threadIdx.x < RDIM) sb1[threadIdx.x] = b1[threadIdx.x];
    if (threadIdx.x < DIM)  sb2[threadIdx.x] = b2[threadIdx.x];
    __syncthreads();

    int r = blockIdx.x * 256 + threadIdx.x;
    float lsum = 0.0f;
    if (r < N_NODES) {
        float e[DIM];
        float4* rowp = (float4*)(out + (long long)r * DIM);
        #pragma unroll
        for (int q = 0; q < DIM / 4; ++q) {
            float4 v = rowp[q];
            e[4 * q + 0] = v.x * 0.25f;
            e[4 * q + 1] = v.y * 0.25f;
            e[4 * q + 2] = v.z * 0.25f;
            e[4 * q + 3] = v.w * 0.25f;
        }
        float h[RDIM];
        #pragma unroll
        for (int j = 0; j < RDIM; ++j) {
            float s = sb1[j];
            #pragma unroll
            for (int d = 0; d < DIM; ++d) s += sw1[j][d] * e[d];
            h[j] = s;
        }
        // compute g 4-at-a-time and store, accumulating loss
        #pragma unroll
        for (int q = 0; q < DIM / 4; ++q) {
            float g[4];
            #pragma unroll
            for (int m = 0; m < 4; ++m) {
                int k = 4 * q + m;
                float s = sb2[k];
                #pragma unroll
                for (int j = 0; j < RDIM; ++j) s += sw2[k][j] * h[j];
                g[m] = s;
                float df = s - e[k];
                lsum += df * df;
            }
            float4 v;
            v.x = g[0]; v.y = g[1]; v.z = g[2]; v.w = g[3];
            rowp[q] = v;
        }
    }

    // block reduction of lsum -> one atomicAdd
    #pragma unroll
    for (int off = 32; off > 0; off >>= 1) lsum += __shfl_down(lsum, off);
    __shared__ float wsum[4];
    if ((threadIdx.x & 63) == 0) wsum[threadIdx.x >> 6] = lsum;
    __syncthreads();
    if (threadIdx.x == 0) {
        atomicAdd(loss, wsum[0] + wsum[1] + wsum[2] + wsum[3]);
    }
}

// ---------------------------------------------------------------------------
extern "C" void kernel_launch(void* const* d_in, const int* in_sizes, int n_in,
                              void* d_out, int out_size, void* d_ws, size_t ws_size,
                              hipStream_t stream) {
    const int*   rows = (const int*)d_in[0];
    const int*   cols = (const int*)d_in[1];
    const float* vals = (const float*)d_in[2];
    const float* ue   = (const float*)d_in[3];
    const float* ie   = (const float*)d_in[4];
    const float* w1   = (const float*)d_in[5];
    const float* b1   = (const float*)d_in[6];
    const float* w2   = (const float*)d_in[7];
    const float* b2   = (const float*)d_in[8];
    float* out = (float*)d_out;

    float* egoA = (float*)d_ws;                 // 38.4 MB
    float* egoB = egoA + EMB_TOT;               // 38.4 MB

    const int VEC_BLOCKS = (EMB_TOT / 4 + 255) / 256;   // 9375

    k_init<<<VEC_BLOCKS, 256, 0, stream>>>((const float4*)ue, (const float4*)ie,
                                           (float4*)egoA, (float4*)out);

    float* cur = egoA;
    float* nxt = egoB;
    for (int l = 0; l < 3; ++l) {
        hipMemsetAsync(nxt, 0, (size_t)EMB_TOT * sizeof(float), stream);
        k_spmm<<<NNZ_E / 4, 256, 0, stream>>>(rows, cols, vals, cur, nxt);
        k_accadd<<<VEC_BLOCKS, 256, 0, stream>>>((const float4*)nxt, (float4*)out);
        float* t = cur; cur = nxt; nxt = t;
    }

    k_zero_loss<<<1, 64, 0, stream>>>(out + EMB_TOT);
    k_mlp_loss<<<(N_NODES + 255) / 256, 256, 0, stream>>>(out, w1, b1, w2, b2,
                                                          out + EMB_TOT);
}

// Round 3
// 1503.293 us; speedup vs baseline: 2.2399x; 2.2399x over previous
//
#include <hip/hip_runtime.h>

#define N_USERS 100000
#define N_ITEMS 50000
#define N_NODES 150000
#define DIM 64
#define RDIM 32
#define NNZ_E 4800000
#define EMB_TOT (N_NODES * DIM)   // 9,600,000 floats
#define SCAN_ELEMS 1024
#define SCAN_BLOCKS ((N_NODES + SCAN_ELEMS - 1) / SCAN_ELEMS)   // 147

// ---------------------------------------------------------------------------
// init: ego = concat(user, item); acc(d_out) = same
// ---------------------------------------------------------------------------
__global__ __launch_bounds__(256) void k_init(const float4* __restrict__ ue,
                                              const float4* __restrict__ ie,
                                              float4* __restrict__ ego,
                                              float4* __restrict__ acc) {
    int i = blockIdx.x * 256 + threadIdx.x;           // over EMB_TOT/4 float4s
    if (i >= EMB_TOT / 4) return;
    const int USER4 = N_USERS * DIM / 4;
    float4 v = (i < USER4) ? ue[i] : ie[i - USER4];
    ego[i] = v;
    acc[i] = v;
}

// ---------------------------------------------------------------------------
// CSR build step 1: histogram of row ids
// ---------------------------------------------------------------------------
__global__ __launch_bounds__(256) void k_count(const int* __restrict__ rows,
                                               int* __restrict__ counts) {
    int e = blockIdx.x * 256 + threadIdx.x;
    if (e < NNZ_E) atomicAdd(&counts[rows[e]], 1);
}

// ---------------------------------------------------------------------------
// CSR build step 2a: per-1024-chunk exclusive scan, block totals to bsum
// ---------------------------------------------------------------------------
__global__ __launch_bounds__(256) void k_scan1(const int* __restrict__ counts,
                                               int* __restrict__ rs,
                                               int* __restrict__ bsum) {
    __shared__ int lds[256];
    int base = blockIdx.x * SCAN_ELEMS + threadIdx.x * 4;
    int c0 = 0, c1 = 0, c2 = 0, c3 = 0;
    if (base + 0 < N_NODES) c0 = counts[base + 0];
    if (base + 1 < N_NODES) c1 = counts[base + 1];
    if (base + 2 < N_NODES) c2 = counts[base + 2];
    if (base + 3 < N_NODES) c3 = counts[base + 3];
    lds[threadIdx.x] = c0 + c1 + c2 + c3;
    __syncthreads();
    for (int off = 1; off < 256; off <<= 1) {
        int v = (threadIdx.x >= off) ? lds[threadIdx.x - off] : 0;
        __syncthreads();
        lds[threadIdx.x] += v;
        __syncthreads();
    }
    int excl = (threadIdx.x == 0) ? 0 : lds[threadIdx.x - 1];
    if (base + 0 < N_NODES) rs[base + 0] = excl;
    if (base + 1 < N_NODES) rs[base + 1] = excl + c0;
    if (base + 2 < N_NODES) rs[base + 2] = excl + c0 + c1;
    if (base + 3 < N_NODES) rs[base + 3] = excl + c0 + c1 + c2;
    if (threadIdx.x == 255) bsum[blockIdx.x] = lds[255];
}

// ---------------------------------------------------------------------------
// CSR build step 2b: exclusive scan of the (147) block totals, in place
// ---------------------------------------------------------------------------
__global__ __launch_bounds__(256) void k_scan2(int* __restrict__ bsum, int nb) {
    __shared__ int lds[256];
    lds[threadIdx.x] = (threadIdx.x < nb) ? bsum[threadIdx.x] : 0;
    __syncthreads();
    for (int off = 1; off < 256; off <<= 1) {
        int v = (threadIdx.x >= off) ? lds[threadIdx.x - off] : 0;
        __syncthreads();
        lds[threadIdx.x] += v;
        __syncthreads();
    }
    int excl = (threadIdx.x == 0) ? 0 : lds[threadIdx.x - 1];
    if (threadIdx.x < nb) bsum[threadIdx.x] = excl;
}

// ---------------------------------------------------------------------------
// CSR build step 2c: add block offsets; init scatter cursors; set sentinel
// ---------------------------------------------------------------------------
__global__ __launch_bounds__(256) void k_scan3(int* __restrict__ rs,
                                               const int* __restrict__ bsum,
                                               int* __restrict__ cursor) {
    int i = blockIdx.x * 256 + threadIdx.x;
    if (i < N_NODES) {
        int v = rs[i] + bsum[i >> 10];   // SCAN_ELEMS == 1024
        rs[i] = v;
        cursor[i] = v;
    }
    if (i == 0) rs[N_NODES] = NNZ_E;
}

// ---------------------------------------------------------------------------
// CSR build step 3: scatter edges into row-sorted interleaved (col,val) array
// ---------------------------------------------------------------------------
__global__ __launch_bounds__(256) void k_scatter(const int* __restrict__ rows,
                                                 const int* __restrict__ cols,
                                                 const float* __restrict__ vals,
                                                 int* __restrict__ cursor,
                                                 uint2* __restrict__ edges) {
    int e = blockIdx.x * 256 + threadIdx.x;
    if (e >= NNZ_E) return;
    int r = rows[e];
    int pos = atomicAdd(&cursor[r], 1);
    edges[pos] = make_uint2((unsigned)cols[e], __float_as_uint(vals[e]));
}

// ---------------------------------------------------------------------------
// CSR SpMM, one wave per row, lane = dim. No atomics; fused acc += y.
// ---------------------------------------------------------------------------
__global__ __launch_bounds__(256) void k_spmm_csr(const uint2* __restrict__ edges,
                                                  const int* __restrict__ rs,
                                                  const float* __restrict__ x,
                                                  float* __restrict__ y,
                                                  float* __restrict__ acc) {
    int wid  = (blockIdx.x * 256 + threadIdx.x) >> 6;
    int lane = threadIdx.x & 63;
    if (wid >= N_NODES) return;
    int start = rs[wid];
    int end   = rs[wid + 1];
    float s = 0.0f;
    for (int base = start; base < end; base += 64) {
        int n = end - base;
        if (n > 64) n = 64;
        uint2 ev = (lane < n) ? edges[base + lane] : make_uint2(0u, 0u);
        int   ec = (int)ev.x;
        float evv = __uint_as_float(ev.y);
        #pragma unroll 4
        for (int j = 0; j < n; ++j) {
            int   c = __shfl(ec, j);
            float v = __shfl(evv, j);
            s += v * x[(long long)c * DIM + lane];
        }
    }
    long long o = (long long)wid * DIM + lane;
    y[o] = s;
    acc[o] += s;
}

// ---------------------------------------------------------------------------
__global__ void k_zero_loss(float* p) {
    if (blockIdx.x == 0 && threadIdx.x == 0) *p = 0.0f;
}

// ---------------------------------------------------------------------------
// final: per-row  e = acc/4 ; h = W1 e + b1 ; g = W2 h + b2 ;
//        out_row = g (in place over acc) ; loss += ||g - e||^2
// ---------------------------------------------------------------------------
__global__ __launch_bounds__(256) void k_mlp_loss(float* __restrict__ out,
                                                  const float* __restrict__ w1,
                                                  const float* __restrict__ b1,
                                                  const float* __restrict__ w2,
                                                  const float* __restrict__ b2,
                                                  float* __restrict__ loss) {
    __shared__ float sw1[RDIM][DIM];   // fc1_w[j][d]
    __shared__ float sw2[DIM][RDIM];   // fc2_w[k][j]
    __shared__ float sb1[RDIM];
    __shared__ float sb2[DIM];

    for (int i = threadIdx.x; i < RDIM * DIM; i += 256) sw1[i / DIM][i % DIM] = w1[i];
    for (int i = threadIdx.x; i < DIM * RDIM; i += 256) sw2[i / RDIM][i % RDIM] = w2[i];
    if (threadIdx.x < RDIM) sb1[threadIdx.x] = b1[threadIdx.x];
    if (threadIdx.x < DIM)  sb2[threadIdx.x] = b2[threadIdx.x];
    __syncthreads();

    int r = blockIdx.x * 256 + threadIdx.x;
    float lsum = 0.0f;
    if (r < N_NODES) {
        float e[DIM];
        float4* rowp = (float4*)(out + (long long)r * DIM);
        #pragma unroll
        for (int q = 0; q < DIM / 4; ++q) {
            float4 v = rowp[q];
            e[4 * q + 0] = v.x * 0.25f;
            e[4 * q + 1] = v.y * 0.25f;
            e[4 * q + 2] = v.z * 0.25f;
            e[4 * q + 3] = v.w * 0.25f;
        }
        float h[RDIM];
        #pragma unroll
        for (int j = 0; j < RDIM; ++j) {
            float s = sb1[j];
            #pragma unroll
            for (int d = 0; d < DIM; ++d) s += sw1[j][d] * e[d];
            h[j] = s;
        }
        #pragma unroll
        for (int q = 0; q < DIM / 4; ++q) {
            float g[4];
            #pragma unroll
            for (int m = 0; m < 4; ++m) {
                int k = 4 * q + m;
                float s = sb2[k];
                #pragma unroll
                for (int j = 0; j < RDIM; ++j) s += sw2[k][j] * h[j];
                g[m] = s;
                float df = s - e[k];
                lsum += df * df;
            }
            float4 v;
            v.x = g[0]; v.y = g[1]; v.z = g[2]; v.w = g[3];
            rowp[q] = v;
        }
    }

    #pragma unroll
    for (int off = 32; off > 0; off >>= 1) lsum += __shfl_down(lsum, off);
    __shared__ float wsum[4];
    if ((threadIdx.x & 63) == 0) wsum[threadIdx.x >> 6] = lsum;
    __syncthreads();
    if (threadIdx.x == 0) {
        atomicAdd(loss, wsum[0] + wsum[1] + wsum[2] + wsum[3]);
    }
}

// ---------------------------------------------------------------------------
extern "C" void kernel_launch(void* const* d_in, const int* in_sizes, int n_in,
                              void* d_out, int out_size, void* d_ws, size_t ws_size,
                              hipStream_t stream) {
    const int*   rows = (const int*)d_in[0];
    const int*   cols = (const int*)d_in[1];
    const float* vals = (const float*)d_in[2];
    const float* ue   = (const float*)d_in[3];
    const float* ie   = (const float*)d_in[4];
    const float* w1   = (const float*)d_in[5];
    const float* b1   = (const float*)d_in[6];
    const float* w2   = (const float*)d_in[7];
    const float* b2   = (const float*)d_in[8];
    float* out = (float*)d_out;

    // workspace layout (~117 MB)
    float* egoA   = (float*)d_ws;                    // 38.4 MB
    float* egoB   = egoA + EMB_TOT;                  // 38.4 MB
    uint2* edges  = (uint2*)(egoB + EMB_TOT);        // 38.4 MB
    int*   rs     = (int*)(edges + NNZ_E);           // N_NODES+1
    int*   cursor = rs + N_NODES + 1;                // N_NODES
    int*   counts = cursor + N_NODES;                // N_NODES
    int*   bsum   = counts + N_NODES;                // 256

    const int VEC_BLOCKS  = (EMB_TOT / 4 + 255) / 256;   // 9375
    const int EDGE_BLOCKS = (NNZ_E + 255) / 256;         // 18750

    k_init<<<VEC_BLOCKS, 256, 0, stream>>>((const float4*)ue, (const float4*)ie,
                                           (float4*)egoA, (float4*)out);

    // ---- CSR build (once per launch; reused by all 3 layers) ----
    hipMemsetAsync(counts, 0, (size_t)N_NODES * sizeof(int), stream);
    k_count<<<EDGE_BLOCKS, 256, 0, stream>>>(rows, counts);
    k_scan1<<<SCAN_BLOCKS, 256, 0, stream>>>(counts, rs, bsum);
    k_scan2<<<1, 256, 0, stream>>>(bsum, SCAN_BLOCKS);
    k_scan3<<<(N_NODES + 255) / 256, 256, 0, stream>>>(rs, bsum, cursor);
    k_scatter<<<EDGE_BLOCKS, 256, 0, stream>>>(rows, cols, vals, cursor, edges);

    // ---- 3 propagation layers, no atomics, fused acc += ----
    float* cur = egoA;
    float* nxt = egoB;
    for (int l = 0; l < 3; ++l) {
        k_spmm_csr<<<(N_NODES * 64 + 255) / 256, 256, 0, stream>>>(edges, rs, cur, nxt, out);
        float* t = cur; cur = nxt; nxt = t;
    }

    k_zero_loss<<<1, 64, 0, stream>>>(out + EMB_TOT);
    k_mlp_loss<<<(N_NODES + 255) / 256, 256, 0, stream>>>(out, w1, b1, w2, b2,
                                                          out + EMB_TOT);
}

// Round 4
// 1209.104 us; speedup vs baseline: 2.7850x; 1.2433x over previous
//
#include <hip/hip_runtime.h>

#define N_USERS 100000
#define N_ITEMS 50000
#define N_NODES 150000
#define DIM 64
#define RDIM 32
#define NNZ_E 4800000
#define EMB_TOT (N_NODES * DIM)          // 9,600,000 floats
#define RPB 128                           // rows per bucket
#define NB ((N_NODES + RPB - 1) / RPB)    // 1172 buckets
#define BPART 128                         // partition blocks
#define TPART 1024                        // partition threads/block

// ---------------------------------------------------------------------------
// init: ego = concat(user, item); acc(d_out) = same
// ---------------------------------------------------------------------------
__global__ __launch_bounds__(256) void k_init(const float4* __restrict__ ue,
                                              const float4* __restrict__ ie,
                                              float4* __restrict__ ego,
                                              float4* __restrict__ acc) {
    int i = blockIdx.x * 256 + threadIdx.x;
    if (i >= EMB_TOT / 4) return;
    const int USER4 = N_USERS * DIM / 4;
    float4 v = (i < USER4) ? ue[i] : ie[i - USER4];
    ego[i] = v;
    acc[i] = v;
}

// ---------------------------------------------------------------------------
// partition 1: per-block bucket histogram (LDS, no global atomics)
// ---------------------------------------------------------------------------
__global__ __launch_bounds__(TPART) void k_hist(const int* __restrict__ rows,
                                                int* __restrict__ hist) {
    __shared__ int h[NB];
    for (int i = threadIdx.x; i < NB; i += TPART) h[i] = 0;
    __syncthreads();
    for (int e = blockIdx.x * TPART + threadIdx.x; e < NNZ_E; e += BPART * TPART)
        atomicAdd(&h[rows[e] >> 7], 1);
    __syncthreads();
    for (int i = threadIdx.x; i < NB; i += TPART)
        hist[blockIdx.x * NB + i] = h[i];
}

// ---------------------------------------------------------------------------
// partition 2a: bucket totals (column sums of hist)
// ---------------------------------------------------------------------------
__global__ __launch_bounds__(256) void k_btot(const int* __restrict__ hist,
                                              int* __restrict__ btot) {
    int b = blockIdx.x * 256 + threadIdx.x;
    if (b >= NB) return;
    int s = 0;
    for (int blk = 0; blk < BPART; ++blk) s += hist[blk * NB + b];
    btot[b] = s;
}

// ---------------------------------------------------------------------------
// partition 2b: exclusive scan of bucket totals -> base[NB+1]; rs sentinel
// ---------------------------------------------------------------------------
__global__ __launch_bounds__(1024) void k_bsum(const int* __restrict__ btot,
                                               int* __restrict__ base,
                                               int* __restrict__ rs) {
    __shared__ int sc[2048];
    int t = threadIdx.x;
    sc[t]        = (t < NB) ? btot[t] : 0;
    sc[t + 1024] = (t + 1024 < NB) ? btot[t + 1024] : 0;
    __syncthreads();
    for (int off = 1; off < 2048; off <<= 1) {
        int v1 = (t >= off) ? sc[t - off] : 0;
        int v2 = (t + 1024 >= off) ? sc[t + 1024 - off] : 0;
        __syncthreads();
        sc[t] += v1;
        sc[t + 1024] += v2;
        __syncthreads();
    }
    if (t < NB)        base[t] = (t == 0) ? 0 : sc[t - 1];
    if (t + 1024 < NB) base[t + 1024] = sc[t + 1023];
    if (t == 0) { base[NB] = NNZ_E; rs[N_NODES] = NNZ_E; }
}

// ---------------------------------------------------------------------------
// partition 2c: convert hist counts -> per-(block,bucket) starting offsets
// ---------------------------------------------------------------------------
__global__ __launch_bounds__(256) void k_off(int* __restrict__ hist,
                                             const int* __restrict__ base) {
    int b = blockIdx.x * 256 + threadIdx.x;
    if (b >= NB) return;
    int run = base[b];
    for (int blk = 0; blk < BPART; ++blk) {
        int c = hist[blk * NB + b];
        hist[blk * NB + b] = run;
        run += c;
    }
}

// ---------------------------------------------------------------------------
// partition 3: scatter edges into bucket-contiguous tmp (LDS cursors).
// payload: x = (row_local<<18) | col (7b + 18b), y = bits(val)
// ---------------------------------------------------------------------------
__global__ __launch_bounds__(TPART) void k_part(const int* __restrict__ rows,
                                                const int* __restrict__ cols,
                                                const float* __restrict__ vals,
                                                const int* __restrict__ hist,
                                                uint2* __restrict__ tmp) {
    __shared__ int cur[NB];
    for (int i = threadIdx.x; i < NB; i += TPART)
        cur[i] = hist[blockIdx.x * NB + i];
    __syncthreads();
    for (int e = blockIdx.x * TPART + threadIdx.x; e < NNZ_E; e += BPART * TPART) {
        int r = rows[e];
        int b = r >> 7;
        int pos = atomicAdd(&cur[b], 1);
        tmp[pos] = make_uint2(((unsigned)(r & 127) << 18) | (unsigned)cols[e],
                              __float_as_uint(vals[e]));
    }
}

// ---------------------------------------------------------------------------
// partition 4: within-bucket counting sort -> exact CSR edges + rs.
// Bucket window ~32KB, L2-resident: clean reads/writes.
// ---------------------------------------------------------------------------
__global__ __launch_bounds__(256) void k_sortbkt(const uint2* __restrict__ tmp,
                                                 const int* __restrict__ base,
                                                 uint2* __restrict__ edges,
                                                 int* __restrict__ rs) {
    int b = blockIdx.x;
    int gbase = base[b];
    int nE = base[b + 1] - gbase;
    int nrows = N_NODES - b * RPB;
    if (nrows > RPB) nrows = RPB;

    __shared__ int cnt[RPB];
    __shared__ int sc[RPB];
    int t = threadIdx.x;
    if (t < RPB) cnt[t] = 0;
    __syncthreads();
    for (int i = t; i < nE; i += 256)
        atomicAdd(&cnt[tmp[gbase + i].x >> 18], 1);
    __syncthreads();
    // inclusive scan of cnt into sc (128 entries, Hillis-Steele)
    if (t < RPB) sc[t] = cnt[t];
    __syncthreads();
    for (int off = 1; off < RPB; off <<= 1) {
        int v = 0;
        if (t < RPB && t >= off) v = sc[t - off];
        __syncthreads();
        if (t < RPB) sc[t] += v;
        __syncthreads();
    }
    if (t < RPB) {
        int excl = (t == 0) ? 0 : sc[t - 1];
        if (t < nrows) rs[b * RPB + t] = gbase + excl;
        cnt[t] = excl;          // reuse as scatter cursor
    }
    __syncthreads();
    for (int i = t; i < nE; i += 256) {
        uint2 u = tmp[gbase + i];
        int rl = u.x >> 18;
        int p = atomicAdd(&cnt[rl], 1);
        edges[gbase + p] = make_uint2(u.x & 0x3FFFFu, u.y);
    }
}

// ---------------------------------------------------------------------------
// CSR SpMM, one wave per row, lane = dim. No atomics; fused acc += y.
// ---------------------------------------------------------------------------
__global__ __launch_bounds__(256) void k_spmm_csr(const uint2* __restrict__ edges,
                                                  const int* __restrict__ rs,
                                                  const float* __restrict__ x,
                                                  float* __restrict__ y,
                                                  float* __restrict__ acc) {
    int wid  = (blockIdx.x * 256 + threadIdx.x) >> 6;
    int lane = threadIdx.x & 63;
    if (wid >= N_NODES) return;
    int start = rs[wid];
    int end   = rs[wid + 1];
    float s = 0.0f;
    for (int base = start; base < end; base += 64) {
        int n = end - base;
        if (n > 64) n = 64;
        uint2 ev = (lane < n) ? edges[base + lane] : make_uint2(0u, 0u);
        int   ec = (int)ev.x;
        float evv = __uint_as_float(ev.y);
        #pragma unroll 4
        for (int j = 0; j < n; ++j) {
            int   c = __shfl(ec, j);
            float v = __shfl(evv, j);
            s += v * x[(long long)c * DIM + lane];
        }
    }
    long long o = (long long)wid * DIM + lane;
    y[o] = s;
    acc[o] += s;
}

// ---------------------------------------------------------------------------
__global__ void k_zero_loss(float* p) {
    if (blockIdx.x == 0 && threadIdx.x == 0) *p = 0.0f;
}

// ---------------------------------------------------------------------------
// final: per-row  e = acc/4 ; h = W1 e + b1 ; g = W2 h + b2 ;
//        out_row = g (in place over acc) ; loss += ||g - e||^2
// ---------------------------------------------------------------------------
__global__ __launch_bounds__(256) void k_mlp_loss(float* __restrict__ out,
                                                  const float* __restrict__ w1,
                                                  const float* __restrict__ b1,
                                                  const float* __restrict__ w2,
                                                  const float* __restrict__ b2,
                                                  float* __restrict__ loss) {
    __shared__ float sw1[RDIM][DIM];
    __shared__ float sw2[DIM][RDIM];
    __shared__ float sb1[RDIM];
    __shared__ float sb2[DIM];

    for (int i = threadIdx.x; i < RDIM * DIM; i += 256) sw1[i / DIM][i % DIM] = w1[i];
    for (int i = threadIdx.x; i < DIM * RDIM; i += 256) sw2[i / RDIM][i % RDIM] = w2[i];
    if (threadIdx.x < RDIM) sb1[threadIdx.x] = b1[threadIdx.x];
    if (threadIdx.x < DIM)  sb2[threadIdx.x] = b2[threadIdx.x];
    __syncthreads();

    int r = blockIdx.x * 256 + threadIdx.x;
    float lsum = 0.0f;
    if (r < N_NODES) {
        float e[DIM];
        float4* rowp = (float4*)(out + (long long)r * DIM);
        #pragma unroll
        for (int q = 0; q < DIM / 4; ++q) {
            float4 v = rowp[q];
            e[4 * q + 0] = v.x * 0.25f;
            e[4 * q + 1] = v.y * 0.25f;
            e[4 * q + 2] = v.z * 0.25f;
            e[4 * q + 3] = v.w * 0.25f;
        }
        float h[RDIM];
        #pragma unroll
        for (int j = 0; j < RDIM; ++j) {
            float s = sb1[j];
            #pragma unroll
            for (int d = 0; d < DIM; ++d) s += sw1[j][d] * e[d];
            h[j] = s;
        }
        #pragma unroll
        for (int q = 0; q < DIM / 4; ++q) {
            float g[4];
            #pragma unroll
            for (int m = 0; m < 4; ++m) {
                int k = 4 * q + m;
                float s = sb2[k];
                #pragma unroll
                for (int j = 0; j < RDIM; ++j) s += sw2[k][j] * h[j];
                g[m] = s;
                float df = s - e[k];
                lsum += df * df;
            }
            float4 v;
            v.x = g[0]; v.y = g[1]; v.z = g[2]; v.w = g[3];
            rowp[q] = v;
        }
    }

    #pragma unroll
    for (int off = 32; off > 0; off >>= 1) lsum += __shfl_down(lsum, off);
    __shared__ float wsum[4];
    if ((threadIdx.x & 63) == 0) wsum[threadIdx.x >> 6] = lsum;
    __syncthreads();
    if (threadIdx.x == 0) {
        atomicAdd(loss, wsum[0] + wsum[1] + wsum[2] + wsum[3]);
    }
}

// ---------------------------------------------------------------------------
extern "C" void kernel_launch(void* const* d_in, const int* in_sizes, int n_in,
                              void* d_out, int out_size, void* d_ws, size_t ws_size,
                              hipStream_t stream) {
    const int*   rows = (const int*)d_in[0];
    const int*   cols = (const int*)d_in[1];
    const float* vals = (const float*)d_in[2];
    const float* ue   = (const float*)d_in[3];
    const float* ie   = (const float*)d_in[4];
    const float* w1   = (const float*)d_in[5];
    const float* b1   = (const float*)d_in[6];
    const float* w2   = (const float*)d_in[7];
    const float* b2   = (const float*)d_in[8];
    float* out = (float*)d_out;

    // workspace layout (~116.5 MB). tmp aliases egoB: tmp is dead before
    // spmm layer-1 writes egoB.
    float* egoA  = (float*)d_ws;                    // 38.4 MB
    float* egoB  = egoA + EMB_TOT;                  // 38.4 MB (aliased by tmp)
    uint2* tmp   = (uint2*)egoB;                    // NNZ_E * 8B = 38.4 MB
    uint2* edges = (uint2*)(egoB + EMB_TOT);        // 38.4 MB
    int*   hist  = (int*)(edges + NNZ_E);           // BPART*NB = 600 KB
    int*   btot  = hist + BPART * NB;               // NB
    int*   base  = btot + NB;                       // NB+1
    int*   rs    = base + NB + 1;                   // N_NODES+1

    const int VEC_BLOCKS = (EMB_TOT / 4 + 255) / 256;   // 9375

    // ---- CSR build: deterministic two-level partition, no global atomics ----
    k_hist<<<BPART, TPART, 0, stream>>>(rows, hist);
    k_btot<<<(NB + 255) / 256, 256, 0, stream>>>(hist, btot);
    k_bsum<<<1, 1024, 0, stream>>>(btot, base, rs);
    k_off<<<(NB + 255) / 256, 256, 0, stream>>>(hist, base);
    k_part<<<BPART, TPART, 0, stream>>>(rows, cols, vals, hist, tmp);
    k_sortbkt<<<NB, 256, 0, stream>>>(tmp, base, edges, rs);

    k_init<<<VEC_BLOCKS, 256, 0, stream>>>((const float4*)ue, (const float4*)ie,
                                           (float4*)egoA, (float4*)out);

    // ---- 3 propagation layers, no atomics, fused acc += ----
    float* cur = egoA;
    float* nxt = egoB;
    for (int l = 0; l < 3; ++l) {
        k_spmm_csr<<<(N_NODES * 64 + 255) / 256, 256, 0, stream>>>(edges, rs, cur, nxt, out);
        float* t = cur; cur = nxt; nxt = t;
    }

    k_zero_loss<<<1, 64, 0, stream>>>(out + EMB_TOT);
    k_mlp_loss<<<(N_NODES + 255) / 256, 256, 0, stream>>>(out, w1, b1, w2, b2,
                                                          out + EMB_TOT);
}